// Round 9
// baseline (356.776 us; speedup 1.0000x reference)
//
#include <hip/hip_runtime.h>
#include <math.h>

#define TT 512
typedef float f32x2 __attribute__((ext_vector_type(2)));

#define LOG2E 1.4426950408889634f

__device__ __forceinline__ float fast_rcp(float v)  { return __builtin_amdgcn_rcpf(v); }
__device__ __forceinline__ float fast_exp2(float v) { return __builtin_amdgcn_exp2f(v); }

// quad_perm DPP: xor1 = [1,0,3,2] = 0xB1 ; xor2 = [2,3,0,1] = 0x4E
template<int CTRL>
__device__ __forceinline__ float dppq(float v) {
    return __int_as_float(__builtin_amdgcn_update_dpp(
        __float_as_int(v), __float_as_int(v), CTRL, 0xF, 0xF, false));
}
#define FMA2(A, B, C) __builtin_elementwise_fma((A), (B), (C))

// One wave per batch. Lane l = 4*j + q (q doubles as k-quarter AND gate id).
// Quad-split-k: each lane reads only k-quarter q of h0/h1 (2 ds_read_b128/step
// instead of 8 -- the kernel was LDS-PIPE-bound: 16 waves/CU x 8 b128 x ~12cyc
// ~= the measured 1500 cyc/step). Lane computes 4-gate partials over its
// quarter; a 2-round cndmask+DPP butterfly leaves gate q's full sum on lane q
// (same layout as before, so the verified activation/state asm is unchanged).
// Weights v64-v111 (per-gate blocks, coalesced 1KB loads), accs v112-127.
__global__ __launch_bounds__(64, 4)
void lstm2_wave(const float* __restrict__ x,
                const float* __restrict__ W_ih0, const float* __restrict__ W_hh0,
                const float* __restrict__ b_ih0, const float* __restrict__ b_hh0,
                const float* __restrict__ W_ih1, const float* __restrict__ W_hh1,
                const float* __restrict__ b_ih1, const float* __restrict__ b_hh1,
                const float* __restrict__ W_fc,  const float* __restrict__ b_fc,
                float* __restrict__ out)
{
    const int l = threadIdx.x;
    const int g = l & 3;           // gate: 0=i,1=f,2=g,3=o  (also k-quarter)
    const int j = l >> 2;          // hidden unit
    const int b = blockIdx.x;
    const int row = g * 16 + j;    // PyTorch gate-order row

    // LDS: floats [0,16) h0 | [16,32) h1 | [32,64) trash | [64,576) x
    __shared__ float lds[576];

    // ---- stage x into LDS (coalesced float4), init h state ----
    const float* xb = x + (size_t)b * TT;
    ((float4*)&lds[64])[l]      = ((const float4*)xb)[l];
    ((float4*)&lds[64])[64 + l] = ((const float4*)xb)[64 + l];
    lds[l] = 0.0f;

    const float wx0 = W_ih0[row];
    const float bb0 = b_ih0[row] + b_hh0[row];
    const float bb1 = b_ih1[row] + b_hh1[row];

    const bool  isT = (g == 2);
    const bool  isF = (g == 1);
    const float Ca  = isT ? (-2.0f * LOG2E) : (-LOG2E);
    const float Aa  = isT ? 2.0f : 1.0f;
    const float Ba  = isT ? -1.0f : 0.0f;
    const float C2P = 2.0f * LOG2E;

    const int wslot = (l & 1) ? (((l & 2) << 3) | j) : (32 + (l >> 1));
    float cs0 = 0.0f, cs1 = 0.0f;

    // ---- peel t = 0 (h,c all zero -> no weight matrices needed) ----
    {
        const float x0 = lds[64];
        const float acc0 = fmaf(x0, wx0, bb0);
        const float acc1 = bb1;
        const float act0 = fmaf(Aa, fast_rcp(1.0f + fast_exp2(acc0 * Ca)), Ba);
        const float act1 = fmaf(Aa, fast_rcp(1.0f + fast_exp2(acc1 * Ca)), Ba);
        const float sw0 = dppq<0x4E>(act0);
        const float xp0 = dppq<0xB1>(act0 * sw0);
        cs0 = xp0;                               // f-lane: i0*g0 ; cs1 stays 0
        const float tin = isF ? cs0 : cs1;
        const float e = fast_exp2(fabsf(tin) * C2P);
        float th = fmaf(-2.0f, fast_rcp(e + 1.0f), 1.0f);
        th = copysignf(th, tin);
        const float hv = (isF ? sw0 : act1) * th; // non-f lanes: tanh(0)=0 -> 0
        lds[wslot] = hv;
    }

    // ---- asm loop: t = 1..511 (511 steps), explicit registers ----
    {
        unsigned base  = (unsigned)(size_t)(void*)&lds[0];
        unsigned had   = base + g * 16;         // h0 quarter addr (h1 at +64)
        unsigned xad   = base + 256 + 4;        // &lds_x[1]
        unsigned wbyte = base + wslot * 4;
        const float* pwa = W_hh0 + l * 4;       // + gate*1024B via imm offset
        const float* pwb = W_ih1 + l * 4;
        const float* pwc = W_hh1 + l * 4;
        unsigned long long mF = __ballot(isF);
        unsigned long long m1 = __ballot((l & 1) != 0);
        unsigned long long m2 = __ballot((l & 2) != 0);

        asm volatile(
            // ---------- prologue: weights -> v64..v111 (per-gate 1KB coalesced) ----------
            "global_load_dwordx4 v[64:67],  %[pwa], off\n"
            "global_load_dwordx4 v[68:71],  %[pwa], off offset:1024\n"
            "global_load_dwordx4 v[72:75],  %[pwa], off offset:2048\n"
            "global_load_dwordx4 v[76:79],  %[pwa], off offset:3072\n"
            "global_load_dwordx4 v[80:83],  %[pwb], off\n"
            "global_load_dwordx4 v[84:87],  %[pwb], off offset:1024\n"
            "global_load_dwordx4 v[88:91],  %[pwb], off offset:2048\n"
            "global_load_dwordx4 v[92:95],  %[pwb], off offset:3072\n"
            "global_load_dwordx4 v[96:99],  %[pwc], off\n"
            "global_load_dwordx4 v[100:103], %[pwc], off offset:1024\n"
            "global_load_dwordx4 v[104:107], %[pwc], off offset:2048\n"
            "global_load_dwordx4 v[108:111], %[pwc], off offset:3072\n"
            "v_mov_b32 v27, %[wbyte]\n"
            "v_mov_b32 v28, %[had]\n"
            "v_mov_b32 v29, %[xad]\n"
            "s_movk_i32 s22, 511\n"
            "s_mov_b32 s20, 0x7fffffff\n"
            "s_mov_b32 s21, 0x4038aa3b\n"        // 2*log2(e)
            "s_waitcnt vmcnt(0)\n"
            "Llstm_%=:\n"
            // ---------- h-quarter + x loads ----------
            "ds_read_b128 v[32:35], v28\n"            // h0[4q..4q+3]
            "ds_read_b128 v[36:39], v28 offset:64\n"  // h1[4q..4q+3]
            "ds_read_b32  v31, v29\n"                 // x[t]
            "v_add_u32 v29, 4, v29\n"
            "s_waitcnt lgkmcnt(0)\n"
            // ---------- 24 packed ops: per-gate quarter dots ----------
            "v_pk_mul_f32 v[112:113], v[64:65], v[32:33]\n"
            "v_pk_mul_f32 v[120:121], v[80:81], v[32:33]\n"
            "v_pk_fma_f32 v[112:113], v[66:67], v[34:35], v[112:113]\n"
            "v_pk_fma_f32 v[120:121], v[82:83], v[34:35], v[120:121]\n"
            "v_pk_fma_f32 v[120:121], v[96:97], v[36:37], v[120:121]\n"
            "v_pk_fma_f32 v[120:121], v[98:99], v[38:39], v[120:121]\n"
            "v_pk_mul_f32 v[114:115], v[68:69], v[32:33]\n"
            "v_pk_mul_f32 v[122:123], v[84:85], v[32:33]\n"
            "v_pk_fma_f32 v[114:115], v[70:71], v[34:35], v[114:115]\n"
            "v_pk_fma_f32 v[122:123], v[86:87], v[34:35], v[122:123]\n"
            "v_pk_fma_f32 v[122:123], v[100:101], v[36:37], v[122:123]\n"
            "v_pk_fma_f32 v[122:123], v[102:103], v[38:39], v[122:123]\n"
            "v_pk_mul_f32 v[116:117], v[72:73], v[32:33]\n"
            "v_pk_mul_f32 v[124:125], v[88:89], v[32:33]\n"
            "v_pk_fma_f32 v[116:117], v[74:75], v[34:35], v[116:117]\n"
            "v_pk_fma_f32 v[124:125], v[90:91], v[34:35], v[124:125]\n"
            "v_pk_fma_f32 v[124:125], v[104:105], v[36:37], v[124:125]\n"
            "v_pk_fma_f32 v[124:125], v[106:107], v[38:39], v[124:125]\n"
            "v_pk_mul_f32 v[118:119], v[76:77], v[32:33]\n"
            "v_pk_mul_f32 v[126:127], v[92:93], v[32:33]\n"
            "v_pk_fma_f32 v[118:119], v[78:79], v[34:35], v[118:119]\n"
            "v_pk_fma_f32 v[126:127], v[94:95], v[34:35], v[126:127]\n"
            "v_pk_fma_f32 v[126:127], v[108:109], v[36:37], v[126:127]\n"
            "v_pk_fma_f32 v[126:127], v[110:111], v[38:39], v[126:127]\n"
            // ---------- horizontal adds (gate partials p0..p3 per layer) ----------
            "v_add_f32 v40, v112, v113\n"
            "v_add_f32 v41, v114, v115\n"
            "v_add_f32 v42, v116, v117\n"
            "v_add_f32 v43, v118, v119\n"
            "v_add_f32 v44, v120, v121\n"
            "v_add_f32 v45, v122, v123\n"
            "v_add_f32 v46, v124, v125\n"
            "v_add_f32 v47, v126, v127\n"
            // ---------- quad reduce round 1 (xor2) ----------
            "v_cndmask_b32 v48, v40, v42, %[m2]\n"
            "v_cndmask_b32 v49, v41, v43, %[m2]\n"
            "v_cndmask_b32 v50, v42, v40, %[m2]\n"
            "v_cndmask_b32 v51, v43, v41, %[m2]\n"
            "v_cndmask_b32 v52, v44, v46, %[m2]\n"
            "v_cndmask_b32 v53, v45, v47, %[m2]\n"
            "v_cndmask_b32 v54, v46, v44, %[m2]\n"
            "v_cndmask_b32 v55, v47, v45, %[m2]\n"
            "v_mov_b32_dpp v50, v50 quad_perm:[2,3,0,1] row_mask:0xf bank_mask:0xf\n"
            "v_mov_b32_dpp v51, v51 quad_perm:[2,3,0,1] row_mask:0xf bank_mask:0xf\n"
            "v_mov_b32_dpp v54, v54 quad_perm:[2,3,0,1] row_mask:0xf bank_mask:0xf\n"
            "v_mov_b32_dpp v55, v55 quad_perm:[2,3,0,1] row_mask:0xf bank_mask:0xf\n"
            "v_add_f32 v48, v48, v50\n"
            "v_add_f32 v49, v49, v51\n"
            "v_add_f32 v52, v52, v54\n"
            "v_add_f32 v53, v53, v55\n"
            // ---------- quad reduce round 2 (xor1) ----------
            "v_cndmask_b32 v56, v48, v49, %[m1]\n"
            "v_cndmask_b32 v57, v49, v48, %[m1]\n"
            "v_cndmask_b32 v58, v52, v53, %[m1]\n"
            "v_cndmask_b32 v59, v53, v52, %[m1]\n"
            "s_nop 0\n"
            "v_mov_b32_dpp v57, v57 quad_perm:[1,0,3,2] row_mask:0xf bank_mask:0xf\n"
            "v_mov_b32_dpp v59, v59 quad_perm:[1,0,3,2] row_mask:0xf bank_mask:0xf\n"
            "v_mov_b32 v60, %[bb0]\n"
            "v_fmac_f32 v60, v31, %[wx0]\n"
            "v_add_f32 v56, v56, v57\n"
            "v_add_f32 v58, v58, v59\n"
            "v_add_f32 v120, v56, v60\n"          // acc0 = red0 + (bb0 + x*wx0)
            "v_add_f32 v121, %[bb1], v58\n"       // acc1 = bb1 + red1
            // ---------- gate activations ----------
            "v_mul_f32 v122, %[Ca], v120\n"
            "v_mul_f32 v123, %[Ca], v121\n"
            "v_exp_f32 v122, v122\n"
            "v_exp_f32 v123, v123\n"
            "v_add_f32 v122, 1.0, v122\n"
            "v_add_f32 v123, 1.0, v123\n"
            "v_rcp_f32 v122, v122\n"
            "v_rcp_f32 v123, v123\n"
            "v_fma_f32 v122, %[Aa], v122, %[Ba]\n"
            "v_fma_f32 v123, %[Aa], v123, %[Ba]\n"
            "s_nop 0\n"
            // ---------- cross-gate combine via DPP ----------
            "v_mov_b32_dpp v124, v122 quad_perm:[2,3,0,1] row_mask:0xf bank_mask:0xf\n"
            "v_mov_b32_dpp v125, v123 quad_perm:[2,3,0,1] row_mask:0xf bank_mask:0xf\n"
            "v_mul_f32 v118, v122, v124\n"
            "v_mul_f32 v119, v123, v125\n"
            "s_nop 0\n"
            "v_mov_b32_dpp v118, v118 quad_perm:[1,0,3,2] row_mask:0xf bank_mask:0xf\n"
            "v_mov_b32_dpp v119, v119 quad_perm:[1,0,3,2] row_mask:0xf bank_mask:0xf\n"
            "v_fma_f32 %[cs0], v122, %[cs0], v118\n"
            "v_fma_f32 %[cs1], v125, %[cs1], v119\n"
            // ---------- shared tanh(c) pass + h write ----------
            "v_cndmask_b32 v126, %[cs1], %[cs0], %[mF]\n"
            "v_mul_f32 v127, s21, |v126|\n"
            "v_exp_f32 v127, v127\n"
            "s_nop 0\n"
            "v_add_f32 v127, 1.0, v127\n"
            "v_rcp_f32 v127, v127\n"
            "s_nop 0\n"
            "v_fma_f32 v127, -2.0, v127, 1.0\n"
            "v_bfi_b32 v127, s20, v127, v126\n"
            "v_cndmask_b32 v126, v123, v124, %[mF]\n"
            "v_mul_f32 v126, v126, v127\n"
            "ds_write_b32 v27, v126\n"
            // ---------- loop ----------
            "s_sub_u32 s22, s22, 1\n"
            "s_cmp_lg_u32 s22, 0\n"
            "s_cbranch_scc1 Llstm_%=\n"
            : [cs0]"+v"(cs0), [cs1]"+v"(cs1)
            : [had]"v"(had), [xad]"v"(xad), [wbyte]"v"(wbyte),
              [pwa]"v"(pwa), [pwb]"v"(pwb), [pwc]"v"(pwc),
              [bb0]"v"(bb0), [bb1]"v"(bb1), [wx0]"v"(wx0),
              [Ca]"v"(Ca), [Aa]"v"(Aa), [Ba]"v"(Ba),
              [mF]"s"(mF), [m1]"s"(m1), [m2]"s"(m2)
            : "memory", "scc", "s20", "s21", "s22",
              "v26","v27","v28","v29","v30","v31","v32","v33","v34","v35",
              "v36","v37","v38","v39","v40","v41","v42","v43","v44","v45",
              "v46","v47","v48","v49","v50","v51","v52","v53","v54","v55",
              "v56","v57","v58","v59","v60","v61","v62","v63","v64","v65",
              "v66","v67","v68","v69","v70","v71","v72","v73","v74","v75",
              "v76","v77","v78","v79","v80","v81","v82","v83","v84","v85",
              "v86","v87","v88","v89","v90","v91","v92","v93","v94","v95",
              "v96","v97","v98","v99","v100","v101","v102","v103","v104","v105",
              "v106","v107","v108","v109","v110","v111","v112","v113","v114","v115",
              "v116","v117","v118","v119","v120","v121","v122","v123","v124","v125",
              "v126","v127");
    }

    // ---- final L1 step (C++, full-row wb/wc reloaded AFTER the asm) ----
    {
        const f32x2* h0p = (const f32x2*)&lds[0];
        const f32x2* h1p = (const f32x2*)&lds[16];
        const f32x2 wb0 = *(const f32x2*)&W_ih1[row*16+ 0], wb1 = *(const f32x2*)&W_ih1[row*16+ 2];
        const f32x2 wb2 = *(const f32x2*)&W_ih1[row*16+ 4], wb3 = *(const f32x2*)&W_ih1[row*16+ 6];
        const f32x2 wb4 = *(const f32x2*)&W_ih1[row*16+ 8], wb5 = *(const f32x2*)&W_ih1[row*16+10];
        const f32x2 wb6 = *(const f32x2*)&W_ih1[row*16+12], wb7 = *(const f32x2*)&W_ih1[row*16+14];
        const f32x2 wc0 = *(const f32x2*)&W_hh1[row*16+ 0], wc1 = *(const f32x2*)&W_hh1[row*16+ 2];
        const f32x2 wc2 = *(const f32x2*)&W_hh1[row*16+ 4], wc3 = *(const f32x2*)&W_hh1[row*16+ 6];
        const f32x2 wc4 = *(const f32x2*)&W_hh1[row*16+ 8], wc5 = *(const f32x2*)&W_hh1[row*16+10];
        const f32x2 wc6 = *(const f32x2*)&W_hh1[row*16+12], wc7 = *(const f32x2*)&W_hh1[row*16+14];
        const f32x2 p0 = h0p[0], p1 = h0p[1], p2 = h0p[2], p3 = h0p[3];
        const f32x2 p4 = h0p[4], p5 = h0p[5], p6 = h0p[6], p7 = h0p[7];
        const f32x2 s0 = h1p[0], s1 = h1p[1], s2 = h1p[2], s3 = h1p[3];
        const f32x2 s4 = h1p[4], s5 = h1p[5], s6 = h1p[6], s7 = h1p[7];
        f32x2 a1 = {bb1, 0.0f};
        a1 = FMA2(wb0, p0, a1); a1 = FMA2(wc0, s0, a1);
        a1 = FMA2(wb1, p1, a1); a1 = FMA2(wc1, s1, a1);
        a1 = FMA2(wb2, p2, a1); a1 = FMA2(wc2, s2, a1);
        a1 = FMA2(wb3, p3, a1); a1 = FMA2(wc3, s3, a1);
        a1 = FMA2(wb4, p4, a1); a1 = FMA2(wc4, s4, a1);
        a1 = FMA2(wb5, p5, a1); a1 = FMA2(wc5, s5, a1);
        a1 = FMA2(wb6, p6, a1); a1 = FMA2(wc6, s6, a1);
        a1 = FMA2(wb7, p7, a1); a1 = FMA2(wc7, s7, a1);
        const float acc1 = a1.x + a1.y;
        const float act1 = fmaf(Aa, fast_rcp(1.0f + fast_exp2(acc1 * Ca)), Ba);
        const float sw1 = dppq<0x4E>(act1);
        const float xp1 = dppq<0xB1>(act1 * sw1);
        cs1 = fmaf(sw1, cs1, xp1);                 // valid on o-lane
        const float e = fast_exp2(fabsf(cs1) * C2P);
        float th = fmaf(-2.0f, fast_rcp(e + 1.0f), 1.0f);
        th = copysignf(th, cs1);
        const float h1fin = act1 * th;             // valid on o-lane

        // FC: out[b] = sum_j h1_j * W_fc[j] + b_fc
        const float wfc = W_fc[j];
        float p = (g == 3) ? h1fin * wfc : 0.0f;
        #pragma unroll
        for (int m = 1; m < 64; m <<= 1) p += __shfl_xor(p, m);
        if (l == 0) out[b] = p + b_fc[0];
    }
}

extern "C" void kernel_launch(void* const* d_in, const int* in_sizes, int n_in,
                              void* d_out, int out_size, void* d_ws, size_t ws_size,
                              hipStream_t stream) {
    const float* x     = (const float*)d_in[0];
    const float* W_ih0 = (const float*)d_in[1];
    const float* W_hh0 = (const float*)d_in[2];
    const float* b_ih0 = (const float*)d_in[3];
    const float* b_hh0 = (const float*)d_in[4];
    const float* W_ih1 = (const float*)d_in[5];
    const float* W_hh1 = (const float*)d_in[6];
    const float* b_ih1 = (const float*)d_in[7];
    const float* b_hh1 = (const float*)d_in[8];
    const float* W_fc  = (const float*)d_in[9];
    const float* b_fc  = (const float*)d_in[10];
    float* out = (float*)d_out;

    dim3 grid(4096), block(64);
    hipLaunchKernelGGL(lstm2_wave, grid, block, 0, stream,
                       x, W_ih0, W_hh0, b_ih0, b_hh0,
                       W_ih1, W_hh1, b_ih1, b_hh1, W_fc, b_fc, out);
}

// Round 10
// 349.464 us; speedup vs baseline: 1.0209x; 1.0209x over previous
//
#include <hip/hip_runtime.h>
#include <math.h>

#define TT 512
typedef float f32x2 __attribute__((ext_vector_type(2)));

#define LOG2E 1.4426950408889634f

__device__ __forceinline__ float fast_rcp(float v)  { return __builtin_amdgcn_rcpf(v); }
__device__ __forceinline__ float fast_exp2(float v) { return __builtin_amdgcn_exp2f(v); }

// quad_perm DPP: xor1 = [1,0,3,2] = 0xB1 ; xor2 = [2,3,0,1] = 0x4E
template<int CTRL>
__device__ __forceinline__ float dppq(float v) {
    return __int_as_float(__builtin_amdgcn_update_dpp(
        __float_as_int(v), __float_as_int(v), CTRL, 0xF, 0xF, false));
}
#define FMA2(A, B, C) __builtin_elementwise_fma((A), (B), (C))

// One wave per batch. Lane l = 4*j + q (q = k-quarter AND gate id).
// Quad-split-k loop in one asm block, registers v24-v111 ONLY (88 regs), and
// NOTHING lives across the asm except cs1: the epilogue recomputes everything
// from a laundered workitem id + fresh loads. R8's failure: clobbers to v127
// + ~20 live-across C++ values -> ~150 VGPR -> 3 waves/SIMD -> latency-bound
// (480-cyc serial chain/step, only ~2.4 chains to hide it). This version
// targets <=120 VGPR -> 4 waves/SIMD -> issue-bound (~234 cyc/step).
__global__ __launch_bounds__(64, 4)
void lstm2_wave(const float* __restrict__ x,
                const float* __restrict__ W_ih0, const float* __restrict__ W_hh0,
                const float* __restrict__ b_ih0, const float* __restrict__ b_hh0,
                const float* __restrict__ W_ih1, const float* __restrict__ W_hh1,
                const float* __restrict__ b_ih1, const float* __restrict__ b_hh1,
                const float* __restrict__ W_fc,  const float* __restrict__ b_fc,
                float* __restrict__ out)
{
    const int l = threadIdx.x;
    const int g = l & 3;           // gate: 0=i,1=f,2=g,3=o  (also k-quarter)
    const int j = l >> 2;          // hidden unit
    const int b = blockIdx.x;
    const int row = g * 16 + j;    // PyTorch gate-order row

    // LDS: floats [0,16) h0 | [16,32) h1 | [32,64) trash | [64,576) x
    __shared__ float lds[576];

    // ---- stage x into LDS (coalesced float4), init h state ----
    const float* xb = x + (size_t)b * TT;
    ((float4*)&lds[64])[l]      = ((const float4*)xb)[l];
    ((float4*)&lds[64])[64 + l] = ((const float4*)xb)[64 + l];
    lds[l] = 0.0f;

    const float wx0 = W_ih0[row];
    const float bb0 = b_ih0[row] + b_hh0[row];
    const float bb1 = b_ih1[row] + b_hh1[row];

    const bool  isT = (g == 2);
    const bool  isF = (g == 1);
    const float Ca  = isT ? (-2.0f * LOG2E) : (-LOG2E);
    const float Aa  = isT ? 2.0f : 1.0f;
    const float Ba  = isT ? -1.0f : 0.0f;
    const float C2P = 2.0f * LOG2E;

    const int wslot = (l & 1) ? (((l & 2) << 3) | j) : (32 + (l >> 1));
    float cs0 = 0.0f, cs1 = 0.0f;

    // ---- peel t = 0 (h,c all zero -> no weight matrices needed) ----
    {
        const float x0 = lds[64];
        const float acc0 = fmaf(x0, wx0, bb0);
        const float acc1 = bb1;
        const float act0 = fmaf(Aa, fast_rcp(1.0f + fast_exp2(acc0 * Ca)), Ba);
        const float act1 = fmaf(Aa, fast_rcp(1.0f + fast_exp2(acc1 * Ca)), Ba);
        const float sw0 = dppq<0x4E>(act0);
        const float xp0 = dppq<0xB1>(act0 * sw0);
        cs0 = xp0;                               // f-lane: i0*g0 ; cs1 stays 0
        const float tin = isF ? cs0 : cs1;
        const float e = fast_exp2(fabsf(tin) * C2P);
        float th = fmaf(-2.0f, fast_rcp(e + 1.0f), 1.0f);
        th = copysignf(th, tin);
        const float hv = (isF ? sw0 : act1) * th; // non-f lanes: tanh(0)=0 -> 0
        lds[wslot] = hv;
    }

    // ---- asm loop: t = 1..511 (511 steps), registers v24-v111 only ----
    {
        unsigned base  = (unsigned)(size_t)(void*)&lds[0];
        unsigned had   = base + g * 16;         // h0 quarter addr (h1 at +64B)
        unsigned xad   = base + 256 + 4;        // &lds_x[1]
        unsigned wbyte = base + wslot * 4;
        const float* pwa = W_hh0 + l * 4;       // + gate*1024B via imm offset
        const float* pwb = W_ih1 + l * 4;
        const float* pwc = W_hh1 + l * 4;
        unsigned long long mF = __ballot(isF);
        unsigned long long m1 = __ballot((l & 1) != 0);
        unsigned long long m2 = __ballot((l & 2) != 0);

        asm volatile(
            // ---------- prologue: weights -> v36..v83 (per-gate 1KB coalesced) ----------
            "global_load_dwordx4 v[36:39], %[pwa], off\n"
            "global_load_dwordx4 v[40:43], %[pwa], off offset:1024\n"
            "global_load_dwordx4 v[44:47], %[pwa], off offset:2048\n"
            "global_load_dwordx4 v[48:51], %[pwa], off offset:3072\n"
            "global_load_dwordx4 v[52:55], %[pwb], off\n"
            "global_load_dwordx4 v[56:59], %[pwb], off offset:1024\n"
            "global_load_dwordx4 v[60:63], %[pwb], off offset:2048\n"
            "global_load_dwordx4 v[64:67], %[pwb], off offset:3072\n"
            "global_load_dwordx4 v[68:71], %[pwc], off\n"
            "global_load_dwordx4 v[72:75], %[pwc], off offset:1024\n"
            "global_load_dwordx4 v[76:79], %[pwc], off offset:2048\n"
            "global_load_dwordx4 v[80:83], %[pwc], off offset:3072\n"
            "v_mov_b32 v24, %[wbyte]\n"
            "v_mov_b32 v25, %[had]\n"
            "v_mov_b32 v26, %[xad]\n"
            "v_mov_b32 v108, %[c0]\n"
            "v_mov_b32 v109, %[c1]\n"
            "s_movk_i32 s22, 511\n"
            "s_mov_b32 s20, 0x7fffffff\n"
            "s_mov_b32 s21, 0x4038aa3b\n"        // 2*log2(e)
            "s_waitcnt vmcnt(0)\n"
            "Llstm_%=:\n"
            // ---------- h-quarter + x loads ----------
            "ds_read_b128 v[28:31], v25\n"            // h0[4q..4q+3]
            "ds_read_b128 v[32:35], v25 offset:64\n"  // h1[4q..4q+3]
            "ds_read_b32  v27, v26\n"                 // x[t]
            "v_add_u32 v26, 4, v26\n"
            "s_waitcnt lgkmcnt(0)\n"
            // ---------- 24 packed ops: per-gate quarter dots ----------
            "v_pk_mul_f32 v[84:85], v[36:37], v[28:29]\n"
            "v_pk_mul_f32 v[92:93], v[52:53], v[28:29]\n"
            "v_pk_fma_f32 v[84:85], v[38:39], v[30:31], v[84:85]\n"
            "v_pk_fma_f32 v[92:93], v[54:55], v[30:31], v[92:93]\n"
            "v_pk_fma_f32 v[92:93], v[68:69], v[32:33], v[92:93]\n"
            "v_pk_fma_f32 v[92:93], v[70:71], v[34:35], v[92:93]\n"
            "v_pk_mul_f32 v[86:87], v[40:41], v[28:29]\n"
            "v_pk_mul_f32 v[94:95], v[56:57], v[28:29]\n"
            "v_pk_fma_f32 v[86:87], v[42:43], v[30:31], v[86:87]\n"
            "v_pk_fma_f32 v[94:95], v[58:59], v[30:31], v[94:95]\n"
            "v_pk_fma_f32 v[94:95], v[72:73], v[32:33], v[94:95]\n"
            "v_pk_fma_f32 v[94:95], v[74:75], v[34:35], v[94:95]\n"
            "v_pk_mul_f32 v[88:89], v[44:45], v[28:29]\n"
            "v_pk_mul_f32 v[96:97], v[60:61], v[28:29]\n"
            "v_pk_fma_f32 v[88:89], v[46:47], v[30:31], v[88:89]\n"
            "v_pk_fma_f32 v[96:97], v[62:63], v[30:31], v[96:97]\n"
            "v_pk_fma_f32 v[96:97], v[76:77], v[32:33], v[96:97]\n"
            "v_pk_fma_f32 v[96:97], v[78:79], v[34:35], v[96:97]\n"
            "v_pk_mul_f32 v[90:91], v[48:49], v[28:29]\n"
            "v_pk_mul_f32 v[98:99], v[64:65], v[28:29]\n"
            "v_pk_fma_f32 v[90:91], v[50:51], v[30:31], v[90:91]\n"
            "v_pk_fma_f32 v[98:99], v[66:67], v[30:31], v[98:99]\n"
            "v_pk_fma_f32 v[98:99], v[80:81], v[32:33], v[98:99]\n"
            "v_pk_fma_f32 v[98:99], v[82:83], v[34:35], v[98:99]\n"
            // ---------- horizontal adds (gate partials per layer) ----------
            "v_add_f32 v100, v84, v85\n"
            "v_add_f32 v101, v86, v87\n"
            "v_add_f32 v102, v88, v89\n"
            "v_add_f32 v103, v90, v91\n"
            "v_add_f32 v104, v92, v93\n"
            "v_add_f32 v105, v94, v95\n"
            "v_add_f32 v106, v96, v97\n"
            "v_add_f32 v107, v98, v99\n"
            // ---------- quad reduce round 1 (xor2) ----------
            "v_cndmask_b32 v84, v100, v102, %[m2]\n"
            "v_cndmask_b32 v85, v101, v103, %[m2]\n"
            "v_cndmask_b32 v86, v102, v100, %[m2]\n"
            "v_cndmask_b32 v87, v103, v101, %[m2]\n"
            "v_cndmask_b32 v88, v104, v106, %[m2]\n"
            "v_cndmask_b32 v89, v105, v107, %[m2]\n"
            "v_cndmask_b32 v90, v106, v104, %[m2]\n"
            "v_cndmask_b32 v91, v107, v105, %[m2]\n"
            "v_mov_b32_dpp v86, v86 quad_perm:[2,3,0,1] row_mask:0xf bank_mask:0xf\n"
            "v_mov_b32_dpp v87, v87 quad_perm:[2,3,0,1] row_mask:0xf bank_mask:0xf\n"
            "v_mov_b32_dpp v90, v90 quad_perm:[2,3,0,1] row_mask:0xf bank_mask:0xf\n"
            "v_mov_b32_dpp v91, v91 quad_perm:[2,3,0,1] row_mask:0xf bank_mask:0xf\n"
            "v_add_f32 v84, v84, v86\n"
            "v_add_f32 v85, v85, v87\n"
            "v_add_f32 v88, v88, v90\n"
            "v_add_f32 v89, v89, v91\n"
            // ---------- quad reduce round 2 (xor1) ----------
            "v_cndmask_b32 v92, v84, v85, %[m1]\n"
            "v_cndmask_b32 v93, v85, v84, %[m1]\n"
            "v_cndmask_b32 v94, v88, v89, %[m1]\n"
            "v_cndmask_b32 v95, v89, v88, %[m1]\n"
            "s_nop 0\n"
            "v_mov_b32_dpp v93, v93 quad_perm:[1,0,3,2] row_mask:0xf bank_mask:0xf\n"
            "v_mov_b32_dpp v95, v95 quad_perm:[1,0,3,2] row_mask:0xf bank_mask:0xf\n"
            "v_mov_b32 v96, %[bb0]\n"
            "v_fmac_f32 v96, v27, %[wx0]\n"
            "v_add_f32 v92, v92, v93\n"
            "v_add_f32 v94, v94, v95\n"
            "v_add_f32 v100, v92, v96\n"          // acc0 = red0 + (bb0 + x*wx0)
            "v_add_f32 v101, %[bb1], v94\n"       // acc1 = bb1 + red1
            // ---------- gate activations ----------
            "v_mul_f32 v102, %[Ca], v100\n"
            "v_mul_f32 v103, %[Ca], v101\n"
            "v_exp_f32 v102, v102\n"
            "v_exp_f32 v103, v103\n"
            "v_add_f32 v102, 1.0, v102\n"
            "v_add_f32 v103, 1.0, v103\n"
            "v_rcp_f32 v102, v102\n"
            "v_rcp_f32 v103, v103\n"
            "v_fma_f32 v102, %[Aa], v102, %[Ba]\n"
            "v_fma_f32 v103, %[Aa], v103, %[Ba]\n"
            "s_nop 0\n"
            // ---------- cross-gate combine via DPP ----------
            "v_mov_b32_dpp v104, v102 quad_perm:[2,3,0,1] row_mask:0xf bank_mask:0xf\n"
            "v_mov_b32_dpp v105, v103 quad_perm:[2,3,0,1] row_mask:0xf bank_mask:0xf\n"
            "v_mul_f32 v106, v102, v104\n"
            "v_mul_f32 v107, v103, v105\n"
            "s_nop 0\n"
            "v_mov_b32_dpp v106, v106 quad_perm:[1,0,3,2] row_mask:0xf bank_mask:0xf\n"
            "v_mov_b32_dpp v107, v107 quad_perm:[1,0,3,2] row_mask:0xf bank_mask:0xf\n"
            "v_fma_f32 v108, v102, v108, v106\n"  // cs0 (valid on f-lane)
            "v_fma_f32 v109, v105, v109, v107\n"  // cs1 (valid on o-lane)
            // ---------- shared tanh(c) pass + h write ----------
            "v_cndmask_b32 v110, v109, v108, %[mF]\n"
            "v_mul_f32 v111, s21, |v110|\n"
            "v_exp_f32 v111, v111\n"
            "s_nop 0\n"
            "v_add_f32 v111, 1.0, v111\n"
            "v_rcp_f32 v111, v111\n"
            "s_nop 0\n"
            "v_fma_f32 v111, -2.0, v111, 1.0\n"
            "v_bfi_b32 v111, s20, v111, v110\n"
            "v_cndmask_b32 v110, v103, v104, %[mF]\n"
            "v_mul_f32 v110, v110, v111\n"
            "ds_write_b32 v24, v110\n"
            // ---------- loop ----------
            "s_sub_u32 s22, s22, 1\n"
            "s_cmp_lg_u32 s22, 0\n"
            "s_cbranch_scc1 Llstm_%=\n"
            "v_mov_b32 %[c1], v109\n"
            : [c1]"+v"(cs1)
            : [had]"v"(had), [xad]"v"(xad), [wbyte]"v"(wbyte),
              [pwa]"v"(pwa), [pwb]"v"(pwb), [pwc]"v"(pwc),
              [bb0]"v"(bb0), [bb1]"v"(bb1), [wx0]"v"(wx0),
              [Ca]"v"(Ca), [Aa]"v"(Aa), [Ba]"v"(Ba), [c0]"v"(cs0),
              [mF]"s"(mF), [m1]"s"(m1), [m2]"s"(m2)
            : "memory", "scc", "s20", "s21", "s22",
              "v24","v25","v26","v27","v28","v29","v30","v31",
              "v32","v33","v34","v35","v36","v37","v38","v39",
              "v40","v41","v42","v43","v44","v45","v46","v47",
              "v48","v49","v50","v51","v52","v53","v54","v55",
              "v56","v57","v58","v59","v60","v61","v62","v63",
              "v64","v65","v66","v67","v68","v69","v70","v71",
              "v72","v73","v74","v75","v76","v77","v78","v79",
              "v80","v81","v82","v83","v84","v85","v86","v87",
              "v88","v89","v90","v91","v92","v93","v94","v95",
              "v96","v97","v98","v99","v100","v101","v102","v103",
              "v104","v105","v106","v107","v108","v109","v110","v111");
    }

    // ---- final L1 step: EVERYTHING recomputed from a laundered lane id so
    //      no C++ value (except cs1) is live across the asm ----
    {
        int l2 = __builtin_amdgcn_workitem_id_x();
        asm("" : "+v"(l2));                      // opaque: blocks CSE with pre-asm values
        const int g2 = l2 & 3, j2 = l2 >> 2;
        const int row2 = g2 * 16 + j2;
        const bool isT2 = (g2 == 2);
        const float Ca2 = isT2 ? (-2.0f * LOG2E) : (-LOG2E);
        const float Aa2 = isT2 ? 2.0f : 1.0f;
        const float Ba2 = isT2 ? -1.0f : 0.0f;
        const float bb1e = b_ih1[row2] + b_hh1[row2];

        const f32x2* h0p = (const f32x2*)&lds[0];
        const f32x2* h1p = (const f32x2*)&lds[16];
        const f32x2 wb0 = *(const f32x2*)&W_ih1[row2*16+ 0], wb1 = *(const f32x2*)&W_ih1[row2*16+ 2];
        const f32x2 wb2 = *(const f32x2*)&W_ih1[row2*16+ 4], wb3 = *(const f32x2*)&W_ih1[row2*16+ 6];
        const f32x2 wb4 = *(const f32x2*)&W_ih1[row2*16+ 8], wb5 = *(const f32x2*)&W_ih1[row2*16+10];
        const f32x2 wb6 = *(const f32x2*)&W_ih1[row2*16+12], wb7 = *(const f32x2*)&W_ih1[row2*16+14];
        const f32x2 wc0 = *(const f32x2*)&W_hh1[row2*16+ 0], wc1 = *(const f32x2*)&W_hh1[row2*16+ 2];
        const f32x2 wc2 = *(const f32x2*)&W_hh1[row2*16+ 4], wc3 = *(const f32x2*)&W_hh1[row2*16+ 6];
        const f32x2 wc4 = *(const f32x2*)&W_hh1[row2*16+ 8], wc5 = *(const f32x2*)&W_hh1[row2*16+10];
        const f32x2 wc6 = *(const f32x2*)&W_hh1[row2*16+12], wc7 = *(const f32x2*)&W_hh1[row2*16+14];
        const f32x2 p0 = h0p[0], p1 = h0p[1], p2 = h0p[2], p3 = h0p[3];
        const f32x2 p4 = h0p[4], p5 = h0p[5], p6 = h0p[6], p7 = h0p[7];
        const f32x2 s0 = h1p[0], s1 = h1p[1], s2 = h1p[2], s3 = h1p[3];
        const f32x2 s4 = h1p[4], s5 = h1p[5], s6 = h1p[6], s7 = h1p[7];
        f32x2 a1 = {bb1e, 0.0f};
        a1 = FMA2(wb0, p0, a1); a1 = FMA2(wc0, s0, a1);
        a1 = FMA2(wb1, p1, a1); a1 = FMA2(wc1, s1, a1);
        a1 = FMA2(wb2, p2, a1); a1 = FMA2(wc2, s2, a1);
        a1 = FMA2(wb3, p3, a1); a1 = FMA2(wc3, s3, a1);
        a1 = FMA2(wb4, p4, a1); a1 = FMA2(wc4, s4, a1);
        a1 = FMA2(wb5, p5, a1); a1 = FMA2(wc5, s5, a1);
        a1 = FMA2(wb6, p6, a1); a1 = FMA2(wc6, s6, a1);
        a1 = FMA2(wb7, p7, a1); a1 = FMA2(wc7, s7, a1);
        const float acc1 = a1.x + a1.y;
        const float act1 = fmaf(Aa2, fast_rcp(1.0f + fast_exp2(acc1 * Ca2)), Ba2);
        const float sw1 = dppq<0x4E>(act1);
        const float xp1 = dppq<0xB1>(act1 * sw1);
        cs1 = fmaf(sw1, cs1, xp1);                 // valid on o-lane
        const float e = fast_exp2(fabsf(cs1) * (2.0f * LOG2E));
        float th = fmaf(-2.0f, fast_rcp(e + 1.0f), 1.0f);
        th = copysignf(th, cs1);
        const float h1fin = act1 * th;             // valid on o-lane

        // FC: out[b] = sum_j h1_j * W_fc[j] + b_fc
        const float wfc = W_fc[j2];
        float p = (g2 == 3) ? h1fin * wfc : 0.0f;
        #pragma unroll
        for (int m = 1; m < 64; m <<= 1) p += __shfl_xor(p, m);
        if (l2 == 0) out[b] = p + b_fc[0];
    }
}

extern "C" void kernel_launch(void* const* d_in, const int* in_sizes, int n_in,
                              void* d_out, int out_size, void* d_ws, size_t ws_size,
                              hipStream_t stream) {
    const float* x     = (const float*)d_in[0];
    const float* W_ih0 = (const float*)d_in[1];
    const float* W_hh0 = (const float*)d_in[2];
    const float* b_ih0 = (const float*)d_in[3];
    const float* b_hh0 = (const float*)d_in[4];
    const float* W_ih1 = (const float*)d_in[5];
    const float* W_hh1 = (const float*)d_in[6];
    const float* b_ih1 = (const float*)d_in[7];
    const float* b_hh1 = (const float*)d_in[8];
    const float* W_fc  = (const float*)d_in[9];
    const float* b_fc  = (const float*)d_in[10];
    float* out = (float*)d_out;

    dim3 grid(4096), block(64);
    hipLaunchKernelGGL(lstm2_wave, grid, block, 0, stream,
                       x, W_ih0, W_hh0, b_ih0, b_hh0,
                       W_ih1, W_hh1, b_ih1, b_hh1, W_fc, b_fc, out);
}

// Round 11
// 235.748 us; speedup vs baseline: 1.5134x; 1.4824x over previous
//
#include <hip/hip_runtime.h>
#include <math.h>

#define TT 512
#define LOG2E 1.4426950408889634f

__device__ __forceinline__ float fast_rcp(float v)  { return __builtin_amdgcn_rcpf(v); }
__device__ __forceinline__ float fast_exp2(float v) { return __builtin_amdgcn_exp2f(v); }

// 2 batches per wave. Lane l: grp=l>>5 (batch), half=(l>>4)&1, j=l&15 (unit).
// half0 owns gate rows {j (i), 32+j (g)}; half1 owns {16+j (f), 48+j (o)} of
// W_hh0/W_ih1/W_hh1 (96 weight floats, v80-v175 explicit). Cell state c lives
// on half0 (c = f_sw*c + i*g); f and o cross via ds_swizzle xor16, issued early
// so their latency hides under the activation trans chain. h written by half0.
// Rationale: rounds 0-9 show wall ~= 512 x serial-chain regardless of instr
// count/occupancy -> this layout minimizes the chain (no gate DPP dance, early
// h0 write) and amortizes it over 2 batches/wave with 2 waves/SIMD.
__global__ __launch_bounds__(64, 2)
void lstm2_wave(const float* __restrict__ x,
                const float* __restrict__ W_ih0, const float* __restrict__ W_hh0,
                const float* __restrict__ b_ih0, const float* __restrict__ b_hh0,
                const float* __restrict__ W_ih1, const float* __restrict__ W_hh1,
                const float* __restrict__ b_ih1, const float* __restrict__ b_hh1,
                const float* __restrict__ W_fc,  const float* __restrict__ b_fc,
                float* __restrict__ out)
{
    const int l    = threadIdx.x;
    const int grp  = l >> 5;         // batch within wave
    const int half = (l >> 4) & 1;   // 0: gates i,g ; 1: gates f,o
    const int j    = l & 15;         // hidden unit
    const int bid  = blockIdx.x;

    const int ra0 = half * 16 + j;   // row of slot0 gate (i or f)
    const int ra1 = ra0 + 32;        // row of slot1 gate (g or o)

    // LDS floats: [0,40) grp0 {h0[16], h1[16], pad8} | [40,80) grp1 | [80,144) trash | [144,1168) x[2][512]
    __shared__ float lds[1168];

    // ---- stage x (2 batches, 1024 floats) coalesced ----
    {
        const float4* xg = (const float4*)(x + (size_t)bid * 1024);
        float4* xl = (float4*)&lds[144];
        xl[l]       = xg[l];
        xl[l + 64]  = xg[l + 64];
        xl[l + 128] = xg[l + 128];
        xl[l + 192] = xg[l + 192];
    }
    __syncthreads();

    const float bb0a = b_ih0[ra0] + b_hh0[ra0];
    const float bb0b = b_ih0[ra1] + b_hh0[ra1];
    const float bb1a = b_ih1[ra0] + b_hh1[ra0];
    const float bb1b = b_ih1[ra1] + b_hh1[ra1];
    const float wxa  = W_ih0[ra0];
    const float wxb  = W_ih0[ra1];
    // slot1 activation consts: half0 -> tanh, half1 -> sigmoid
    const float Ca1 = half ? (-LOG2E) : (-2.0f * LOG2E);
    const float Aa1 = half ? 1.0f : 2.0f;
    const float Ba1 = half ? 0.0f : -1.0f;
    const float nl2e = -LOG2E;

    const int widx = half ? (80 + grp * 32 + j) : (grp * 40 + j);   // write slot (h0; h1 at +16)

    // ---- peel t = 0 (h,c = 0: gates from bias + x only) ----
    float cs0, cs1 = 0.0f;
    {
        const float x0 = lds[144 + grp * 512];
        const float a_s0 = fmaf(x0, wxa, bb0a);
        const float a_s1 = fmaf(x0, wxb, bb0b);
        const float s0 = fast_rcp(1.0f + fast_exp2(a_s0 * nl2e));            // i (h0) / f (h1)
        const float s1 = fmaf(Aa1, fast_rcp(1.0f + fast_exp2(a_s1 * Ca1)), Ba1); // g / o
        const float p0 = s0 * s1;              // half0: i*g
        cs0 = p0;                              // c0 = f*0 + i*g  (valid on half0)
        const float e = fast_exp2(fabsf(cs0) * (2.0f * LOG2E));
        float th = fmaf(-2.0f, fast_rcp(e + 1.0f), 1.0f);
        th = copysignf(th, cs0);
        const float osw = __shfl_xor(s1, 16);  // half0 receives o
        const float h0v = osw * th;            // valid on half0
        lds[widx]      = h0v;                  // half1 lands in trash
        lds[widx + 16] = 0.0f;                 // h1 = 0
    }

    // ---- asm loop: t = 1..511. Explicit regs v24-v177. ----
    {
        unsigned base = (unsigned)(size_t)(void*)&lds[0];
        unsigned hb   = base + grp * 160;                 // h read base (bytes)
        unsigned xa   = base + 576 + grp * 2048 + 4;      // &x[grp][1]
        unsigned wb_  = base + widx * 4;                  // write addr
        const float* pwa = W_hh0 + ra0 * 16;              // slot1 row at +2048B
        const float* pwb = W_ih1 + ra0 * 16;
        const float* pwc = W_hh1 + ra0 * 16;

        asm volatile(
            // ---------- prologue ----------
            "s_waitcnt lgkmcnt(0)\n"
            "global_load_dwordx4 v[80:83],   %[pwa], off\n"
            "global_load_dwordx4 v[84:87],   %[pwa], off offset:16\n"
            "global_load_dwordx4 v[88:91],   %[pwa], off offset:32\n"
            "global_load_dwordx4 v[92:95],   %[pwa], off offset:48\n"
            "global_load_dwordx4 v[96:99],   %[pwa], off offset:2048\n"
            "global_load_dwordx4 v[100:103], %[pwa], off offset:2064\n"
            "global_load_dwordx4 v[104:107], %[pwa], off offset:2080\n"
            "global_load_dwordx4 v[108:111], %[pwa], off offset:2096\n"
            "global_load_dwordx4 v[112:115], %[pwb], off\n"
            "global_load_dwordx4 v[116:119], %[pwb], off offset:16\n"
            "global_load_dwordx4 v[120:123], %[pwb], off offset:32\n"
            "global_load_dwordx4 v[124:127], %[pwb], off offset:48\n"
            "global_load_dwordx4 v[128:131], %[pwb], off offset:2048\n"
            "global_load_dwordx4 v[132:135], %[pwb], off offset:2064\n"
            "global_load_dwordx4 v[136:139], %[pwb], off offset:2080\n"
            "global_load_dwordx4 v[140:143], %[pwb], off offset:2096\n"
            "global_load_dwordx4 v[144:147], %[pwc], off\n"
            "global_load_dwordx4 v[148:151], %[pwc], off offset:16\n"
            "global_load_dwordx4 v[152:155], %[pwc], off offset:32\n"
            "global_load_dwordx4 v[156:159], %[pwc], off offset:48\n"
            "global_load_dwordx4 v[160:163], %[pwc], off offset:2048\n"
            "global_load_dwordx4 v[164:167], %[pwc], off offset:2064\n"
            "global_load_dwordx4 v[168:171], %[pwc], off offset:2080\n"
            "global_load_dwordx4 v[172:175], %[pwc], off offset:2096\n"
            "v_mov_b32 v24, %[wb]\n"
            "v_mov_b32 v25, %[hb]\n"
            "v_mov_b32 v26, %[xa]\n"
            "v_mov_b32 v176, %[c0i]\n"
            "v_mov_b32 v177, %[c1]\n"
            "s_movk_i32 s22, 511\n"
            "s_mov_b32 s20, 0x7fffffff\n"
            "s_mov_b32 s21, 0x4038aa3b\n"       // 2*log2(e)
            "s_waitcnt vmcnt(0)\n"
            "Llstm_%=:\n"
            // ---------- loads ----------
            "ds_read_b128 v[32:35], v25\n"             // h0[0:4)
            "ds_read_b128 v[36:39], v25 offset:16\n"
            "ds_read_b128 v[40:43], v25 offset:32\n"
            "ds_read_b128 v[44:47], v25 offset:48\n"
            "ds_read_b128 v[48:51], v25 offset:64\n"   // h1[0:4)
            "ds_read_b128 v[52:55], v25 offset:80\n"
            "ds_read_b128 v[56:59], v25 offset:96\n"
            "ds_read_b128 v[60:63], v25 offset:112\n"
            "ds_read_b32  v27, v26\n"                  // x[t]
            "v_add_u32 v26, 4, v26\n"
            "s_waitcnt lgkmcnt(5)\n"                   // h0 quads ready
            // ---------- L0 dots: acc0a = wa_r0 . h0 ; acc0b = wa_r1 . h0 ----------
            "v_pk_mul_f32 v[64:65], v[80:81],  v[32:33]\n"
            "v_pk_mul_f32 v[66:67], v[96:97],  v[32:33]\n"
            "v_pk_fma_f32 v[64:65], v[82:83],  v[34:35], v[64:65]\n"
            "v_pk_fma_f32 v[66:67], v[98:99],  v[34:35], v[66:67]\n"
            "v_pk_fma_f32 v[64:65], v[84:85],  v[36:37], v[64:65]\n"
            "v_pk_fma_f32 v[66:67], v[100:101], v[36:37], v[66:67]\n"
            "v_pk_fma_f32 v[64:65], v[86:87],  v[38:39], v[64:65]\n"
            "v_pk_fma_f32 v[66:67], v[102:103], v[38:39], v[66:67]\n"
            "v_pk_fma_f32 v[64:65], v[88:89],  v[40:41], v[64:65]\n"
            "v_pk_fma_f32 v[66:67], v[104:105], v[40:41], v[66:67]\n"
            "v_pk_fma_f32 v[64:65], v[90:91],  v[42:43], v[64:65]\n"
            "v_pk_fma_f32 v[66:67], v[106:107], v[42:43], v[66:67]\n"
            "v_pk_fma_f32 v[64:65], v[92:93],  v[44:45], v[64:65]\n"
            "v_pk_fma_f32 v[66:67], v[108:109], v[44:45], v[66:67]\n"
            "v_pk_fma_f32 v[64:65], v[94:95],  v[46:47], v[64:65]\n"
            "v_pk_fma_f32 v[66:67], v[110:111], v[46:47], v[66:67]\n"
            // ---------- L0 finish + acts ----------
            "s_waitcnt lgkmcnt(0)\n"                   // h1 + x ready
            "v_add_f32 v28, v64, v65\n"
            "v_add_f32 v29, v66, v67\n"
            "v_add_f32 v28, %[bb0a], v28\n"
            "v_add_f32 v29, %[bb0b], v29\n"
            "v_fmac_f32 v28, v27, %[wxa]\n"
            "v_fmac_f32 v29, v27, %[wxb]\n"
            "v_mul_f32 v72, %[nl2e], v28\n"
            "v_mul_f32 v73, %[Ca1], v29\n"
            "v_exp_f32 v72, v72\n"
            "v_exp_f32 v73, v73\n"
            "v_add_f32 v72, 1.0, v72\n"
            "v_add_f32 v73, 1.0, v73\n"
            "v_rcp_f32 v72, v72\n"
            "v_rcp_f32 v73, v73\n"
            "ds_swizzle_b32 v76, v72 offset:0x401F\n"  // f0 -> half0
            "v_fma_f32 v73, %[Aa1], v73, %[Ba1]\n"
            "ds_swizzle_b32 v77, v73 offset:0x401F\n"  // o0 -> half0
            "v_mul_f32 v28, v72, v73\n"                // p0 = i0*g0 (half0)
            // ---------- L1 dots (fill swizzle/trans latency) ----------
            "v_pk_mul_f32 v[68:69], v[112:113], v[32:33]\n"
            "v_pk_mul_f32 v[70:71], v[128:129], v[32:33]\n"
            "v_pk_fma_f32 v[68:69], v[114:115], v[34:35], v[68:69]\n"
            "v_pk_fma_f32 v[70:71], v[130:131], v[34:35], v[70:71]\n"
            "v_pk_fma_f32 v[68:69], v[116:117], v[36:37], v[68:69]\n"
            "v_pk_fma_f32 v[70:71], v[132:133], v[36:37], v[70:71]\n"
            "v_pk_fma_f32 v[68:69], v[118:119], v[38:39], v[68:69]\n"
            "v_pk_fma_f32 v[70:71], v[134:135], v[38:39], v[70:71]\n"
            "v_pk_fma_f32 v[68:69], v[120:121], v[40:41], v[68:69]\n"
            "v_pk_fma_f32 v[70:71], v[136:137], v[40:41], v[70:71]\n"
            "v_pk_fma_f32 v[68:69], v[122:123], v[42:43], v[68:69]\n"
            "v_pk_fma_f32 v[70:71], v[138:139], v[42:43], v[70:71]\n"
            "v_pk_fma_f32 v[68:69], v[124:125], v[44:45], v[68:69]\n"
            "v_pk_fma_f32 v[70:71], v[140:141], v[44:45], v[70:71]\n"
            "v_pk_fma_f32 v[68:69], v[126:127], v[46:47], v[68:69]\n"
            "v_pk_fma_f32 v[70:71], v[142:143], v[46:47], v[70:71]\n"
            "v_pk_fma_f32 v[68:69], v[144:145], v[48:49], v[68:69]\n"
            "v_pk_fma_f32 v[70:71], v[160:161], v[48:49], v[70:71]\n"
            "v_pk_fma_f32 v[68:69], v[146:147], v[50:51], v[68:69]\n"
            "v_pk_fma_f32 v[70:71], v[162:163], v[50:51], v[70:71]\n"
            "v_pk_fma_f32 v[68:69], v[148:149], v[52:53], v[68:69]\n"
            "v_pk_fma_f32 v[70:71], v[164:165], v[52:53], v[70:71]\n"
            "v_pk_fma_f32 v[68:69], v[150:151], v[54:55], v[68:69]\n"
            "v_pk_fma_f32 v[70:71], v[166:167], v[54:55], v[70:71]\n"
            "v_pk_fma_f32 v[68:69], v[152:153], v[56:57], v[68:69]\n"
            "v_pk_fma_f32 v[70:71], v[168:169], v[56:57], v[70:71]\n"
            "v_pk_fma_f32 v[68:69], v[154:155], v[58:59], v[68:69]\n"
            "v_pk_fma_f32 v[70:71], v[170:171], v[58:59], v[70:71]\n"
            "v_pk_fma_f32 v[68:69], v[156:157], v[60:61], v[68:69]\n"
            "v_pk_fma_f32 v[70:71], v[172:173], v[60:61], v[70:71]\n"
            "v_pk_fma_f32 v[68:69], v[158:159], v[62:63], v[68:69]\n"
            "v_pk_fma_f32 v[70:71], v[174:175], v[62:63], v[70:71]\n"
            // ---------- L1 finish + acts ----------
            "v_add_f32 v30, v68, v69\n"
            "v_add_f32 v31, v70, v71\n"
            "v_add_f32 v30, %[bb1a], v30\n"
            "v_add_f32 v31, %[bb1b], v31\n"
            "v_mul_f32 v74, %[nl2e], v30\n"
            "v_mul_f32 v75, %[Ca1], v31\n"
            "v_exp_f32 v74, v74\n"
            "v_exp_f32 v75, v75\n"
            "v_add_f32 v74, 1.0, v74\n"
            "v_add_f32 v75, 1.0, v75\n"
            "v_rcp_f32 v74, v74\n"
            "v_rcp_f32 v75, v75\n"
            "ds_swizzle_b32 v78, v74 offset:0x401F\n"  // f1 -> half0
            "v_fma_f32 v75, %[Aa1], v75, %[Ba1]\n"
            "ds_swizzle_b32 v79, v75 offset:0x401F\n"  // o1 -> half0
            "v_mul_f32 v30, v74, v75\n"                // p1 = i1*g1 (half0)
            // ---------- c0 / tanh / h0 (early write) ----------
            "s_waitcnt lgkmcnt(2)\n"                   // f0,o0 done
            "v_fma_f32 v176, v76, v176, v28\n"         // c0 = f0*c0 + i0*g0
            "v_mul_f32 v29, s21, |v176|\n"
            "v_exp_f32 v29, v29\n"
            "s_nop 0\n"
            "v_add_f32 v29, 1.0, v29\n"
            "v_rcp_f32 v29, v29\n"
            "s_nop 0\n"
            "v_fma_f32 v29, -2.0, v29, 1.0\n"
            "v_bfi_b32 v29, s20, v29, v176\n"
            "v_mul_f32 v28, v77, v29\n"                // h0n = o0 * tanh(c0)
            "ds_write_b32 v24, v28\n"
            // ---------- c1 / tanh / h1 ----------
            "s_waitcnt lgkmcnt(1)\n"                   // f1,o1 done (write outstanding)
            "v_fma_f32 v177, v78, v177, v30\n"         // c1 = f1*c1 + i1*g1
            "v_mul_f32 v29, s21, |v177|\n"
            "v_exp_f32 v29, v29\n"
            "s_nop 0\n"
            "v_add_f32 v29, 1.0, v29\n"
            "v_rcp_f32 v29, v29\n"
            "s_nop 0\n"
            "v_fma_f32 v29, -2.0, v29, 1.0\n"
            "v_bfi_b32 v29, s20, v29, v177\n"
            "v_mul_f32 v29, v79, v29\n"                // h1n = o1 * tanh(c1)
            "ds_write_b32 v24, v29 offset:64\n"
            // ---------- loop ----------
            "s_sub_u32 s22, s22, 1\n"
            "s_cmp_lg_u32 s22, 0\n"
            "s_cbranch_scc1 Llstm_%=\n"
            "v_mov_b32 %[c1], v177\n"
            : [c1]"+v"(cs1)
            : [hb]"v"(hb), [xa]"v"(xa), [wb]"v"(wb_),
              [pwa]"v"(pwa), [pwb]"v"(pwb), [pwc]"v"(pwc),
              [bb0a]"v"(bb0a), [bb0b]"v"(bb0b), [bb1a]"v"(bb1a), [bb1b]"v"(bb1b),
              [wxa]"v"(wxa), [wxb]"v"(wxb), [nl2e]"v"(nl2e),
              [Ca1]"v"(Ca1), [Aa1]"v"(Aa1), [Ba1]"v"(Ba1), [c0i]"v"(cs0)
            : "memory", "scc", "s20", "s21", "s22",
              "v24","v25","v26","v27","v28","v29","v30","v31",
              "v32","v33","v34","v35","v36","v37","v38","v39",
              "v40","v41","v42","v43","v44","v45","v46","v47",
              "v48","v49","v50","v51","v52","v53","v54","v55",
              "v56","v57","v58","v59","v60","v61","v62","v63",
              "v64","v65","v66","v67","v68","v69","v70","v71",
              "v72","v73","v74","v75","v76","v77","v78","v79",
              "v80","v81","v82","v83","v84","v85","v86","v87",
              "v88","v89","v90","v91","v92","v93","v94","v95",
              "v96","v97","v98","v99","v100","v101","v102","v103",
              "v104","v105","v106","v107","v108","v109","v110","v111",
              "v112","v113","v114","v115","v116","v117","v118","v119",
              "v120","v121","v122","v123","v124","v125","v126","v127",
              "v128","v129","v130","v131","v132","v133","v134","v135",
              "v136","v137","v138","v139","v140","v141","v142","v143",
              "v144","v145","v146","v147","v148","v149","v150","v151",
              "v152","v153","v154","v155","v156","v157","v158","v159",
              "v160","v161","v162","v163","v164","v165","v166","v167",
              "v168","v169","v170","v171","v172","v173","v174","v175",
              "v176","v177");
    }

    // ---- final L1 step (t=511): recomputed from laundered lane id ----
    {
        int l2 = __builtin_amdgcn_workitem_id_x();
        asm("" : "+v"(l2));                    // block CSE with pre-asm values
        const int grp2  = l2 >> 5;
        const int half2 = (l2 >> 4) & 1;
        const int j2    = l2 & 15;
        const int rb0 = half2 * 16 + j2;
        const int rb1 = rb0 + 32;
        const float Ca2 = half2 ? (-LOG2E) : (-2.0f * LOG2E);
        const float Aa2 = half2 ? 1.0f : 2.0f;
        const float Ba2 = half2 ? 0.0f : -1.0f;

        float a1a = b_ih1[rb0] + b_hh1[rb0];
        float a1b = b_ih1[rb1] + b_hh1[rb1];
        const float* h0p = &lds[grp2 * 40];
        const float* h1p = h0p + 16;
        #pragma unroll
        for (int k = 0; k < 16; ++k) {
            const float h0k = h0p[k], h1k = h1p[k];
            a1a = fmaf(W_ih1[rb0 * 16 + k], h0k, a1a);
            a1b = fmaf(W_ih1[rb1 * 16 + k], h0k, a1b);
            a1a = fmaf(W_hh1[rb0 * 16 + k], h1k, a1a);
            a1b = fmaf(W_hh1[rb1 * 16 + k], h1k, a1b);
        }
        const float s0 = fast_rcp(1.0f + fast_exp2(a1a * (-LOG2E)));           // i1 / f1
        const float s1 = fmaf(Aa2, fast_rcp(1.0f + fast_exp2(a1b * Ca2)), Ba2); // g1 / o1
        const float p1  = s0 * s1;                    // half0: i1*g1
        const float fsw = __shfl_xor(s0, 16);         // half0 receives f1
        const float osw = __shfl_xor(s1, 16);         // half0 receives o1
        const float c1f = fmaf(fsw, cs1, p1);         // valid on half0
        const float e = fast_exp2(fabsf(c1f) * (2.0f * LOG2E));
        float th = fmaf(-2.0f, fast_rcp(e + 1.0f), 1.0f);
        th = copysignf(th, c1f);
        const float h1fin = osw * th;                 // valid on half0

        // FC: out[2*bid+grp] = sum_j h1_j * W_fc[j] + b_fc
        float p = (half2 == 0) ? h1fin * W_fc[j2] : 0.0f;
        p += __shfl_xor(p, 1);
        p += __shfl_xor(p, 2);
        p += __shfl_xor(p, 4);
        p += __shfl_xor(p, 8);
        p += __shfl_xor(p, 16);
        if ((l2 & 31) == 0) out[2 * bid + grp2] = p + b_fc[0];
    }
}

extern "C" void kernel_launch(void* const* d_in, const int* in_sizes, int n_in,
                              void* d_out, int out_size, void* d_ws, size_t ws_size,
                              hipStream_t stream) {
    const float* x     = (const float*)d_in[0];
    const float* W_ih0 = (const float*)d_in[1];
    const float* W_hh0 = (const float*)d_in[2];
    const float* b_ih0 = (const float*)d_in[3];
    const float* b_hh0 = (const float*)d_in[4];
    const float* W_ih1 = (const float*)d_in[5];
    const float* W_hh1 = (const float*)d_in[6];
    const float* b_ih1 = (const float*)d_in[7];
    const float* b_hh1 = (const float*)d_in[8];
    const float* W_fc  = (const float*)d_in[9];
    const float* b_fc  = (const float*)d_in[10];
    float* out = (float*)d_out;

    dim3 grid(2048), block(64);
    hipLaunchKernelGGL(lstm2_wave, grid, block, 0, stream,
                       x, W_ih0, W_hh0, b_ih0, b_hh0,
                       W_ih1, W_hh1, b_ih1, b_hh1, W_fc, b_fc, out);
}

// Round 12
// 229.285 us; speedup vs baseline: 1.5560x; 1.0282x over previous
//
#include <hip/hip_runtime.h>
#include <math.h>

#define TT 512
#define LOG2E 1.4426950408889634f

__device__ __forceinline__ float fast_rcp(float v)  { return __builtin_amdgcn_rcpf(v); }
__device__ __forceinline__ float fast_exp2(float v) { return __builtin_amdgcn_exp2f(v); }

// 2 batches per wave. Lane l: grp=l>>5 (batch), half=(l>>4)&1, j=l&15 (unit).
// half0 owns gate rows {i(j), g(j)}; half1 owns {f(j), o(j)} of each matrix.
// SINGLE crossing per layer: half0 computes p = i*g, one ds_swizzle(xor16)
// ships p to half1; c = f*c + p, tanh, h = o*tanh(c) all LOCAL on half1
// (R10 shipped f AND o to half0: 2 swizzles/layer + o-wait on the h chain).
// Bias pairs {bb,0} folded into the C operand of the first pk_fma.
// L0 state-update is sandwiched between the two 16-pk halves of the L1 dot
// block so dots hide the swizzle + transcendental latency.
__global__ __launch_bounds__(64, 2)
void lstm2_wave(const float* __restrict__ x,
                const float* __restrict__ W_ih0, const float* __restrict__ W_hh0,
                const float* __restrict__ b_ih0, const float* __restrict__ b_hh0,
                const float* __restrict__ W_ih1, const float* __restrict__ W_hh1,
                const float* __restrict__ b_ih1, const float* __restrict__ b_hh1,
                const float* __restrict__ W_fc,  const float* __restrict__ b_fc,
                float* __restrict__ out)
{
    const int l    = threadIdx.x;
    const int grp  = l >> 5;         // batch within wave
    const int half = (l >> 4) & 1;   // 0: gates i,g ; 1: gates f,o
    const int j    = l & 15;         // hidden unit
    const int bid  = blockIdx.x;

    const int ra0 = half * 16 + j;   // slot0 row (i or f)
    const int ra1 = ra0 + 32;        // slot1 row (g or o)

    // LDS floats: [0,40) grp0 {h0[16], h1[16], pad8} | [40,80) grp1 | [80,144) trash | [144,1168) x[2][512]
    __shared__ float lds[1168];

    // ---- stage x (2 batches, 1024 floats) coalesced ----
    {
        const float4* xg = (const float4*)(x + (size_t)bid * 1024);
        float4* xl = (float4*)&lds[144];
        xl[l]       = xg[l];
        xl[l + 64]  = xg[l + 64];
        xl[l + 128] = xg[l + 128];
        xl[l + 192] = xg[l + 192];
    }
    __syncthreads();

    const float bb0a = b_ih0[ra0] + b_hh0[ra0];
    const float bb0b = b_ih0[ra1] + b_hh0[ra1];
    const float bb1a = b_ih1[ra0] + b_hh1[ra0];
    const float bb1b = b_ih1[ra1] + b_hh1[ra1];
    const float wxa  = W_ih0[ra0];
    const float wxb  = W_ih0[ra1];
    // slot1 activation consts: half0 -> tanh (g), half1 -> sigmoid (o)
    const float Ca1 = half ? (-LOG2E) : (-2.0f * LOG2E);
    const float Aa1 = half ? 1.0f : 2.0f;
    const float Ba1 = half ? 0.0f : -1.0f;
    const float nl2e = -LOG2E;

    // half1 writes real h; half0 writes trash
    const int widx = half ? (grp * 40 + j) : (80 + grp * 32 + j);

    // ---- peel t = 0 (h,c = 0: gates from bias + x only) ----
    float cs0, cs1 = 0.0f;
    {
        const float x0 = lds[144 + grp * 512];
        const float a_s0 = fmaf(x0, wxa, bb0a);
        const float a_s1 = fmaf(x0, wxb, bb0b);
        const float s0 = fast_rcp(1.0f + fast_exp2(a_s0 * nl2e));                 // i / f
        const float s1 = fmaf(Aa1, fast_rcp(1.0f + fast_exp2(a_s1 * Ca1)), Ba1);  // g / o
        const float p  = s0 * s1;               // half0: i*g
        const float psw = __shfl_xor(p, 16);    // half1 receives i*g
        cs0 = psw;                              // c0 = f*0 + i*g (valid on half1)
        const float e = fast_exp2(fabsf(cs0) * (2.0f * LOG2E));
        float th = fmaf(-2.0f, fast_rcp(e + 1.0f), 1.0f);
        th = copysignf(th, cs0);
        const float h0v = s1 * th;              // half1: o * tanh(c0)
        lds[widx]      = h0v;                   // half0 lands in trash
        lds[widx + 16] = 0.0f;                  // h1 = 0
    }

    // ---- asm loop: t = 1..511. Explicit regs v24-v185. ----
    {
        unsigned base = (unsigned)(size_t)(void*)&lds[0];
        unsigned hb   = base + grp * 160;                 // h read base (bytes)
        unsigned xa   = base + 576 + grp * 2048 + 4;      // &x[grp][1]
        unsigned wb_  = base + widx * 4;                  // write addr
        const float* pwa = W_hh0 + ra0 * 16;              // slot1 row at +2048B
        const float* pwb = W_ih1 + ra0 * 16;
        const float* pwc = W_hh1 + ra0 * 16;

        asm volatile(
            // ---------- prologue ----------
            "s_waitcnt lgkmcnt(0)\n"
            "global_load_dwordx4 v[80:83],   %[pwa], off\n"
            "global_load_dwordx4 v[84:87],   %[pwa], off offset:16\n"
            "global_load_dwordx4 v[88:91],   %[pwa], off offset:32\n"
            "global_load_dwordx4 v[92:95],   %[pwa], off offset:48\n"
            "global_load_dwordx4 v[96:99],   %[pwa], off offset:2048\n"
            "global_load_dwordx4 v[100:103], %[pwa], off offset:2064\n"
            "global_load_dwordx4 v[104:107], %[pwa], off offset:2080\n"
            "global_load_dwordx4 v[108:111], %[pwa], off offset:2096\n"
            "global_load_dwordx4 v[112:115], %[pwb], off\n"
            "global_load_dwordx4 v[116:119], %[pwb], off offset:16\n"
            "global_load_dwordx4 v[120:123], %[pwb], off offset:32\n"
            "global_load_dwordx4 v[124:127], %[pwb], off offset:48\n"
            "global_load_dwordx4 v[128:131], %[pwb], off offset:2048\n"
            "global_load_dwordx4 v[132:135], %[pwb], off offset:2064\n"
            "global_load_dwordx4 v[136:139], %[pwb], off offset:2080\n"
            "global_load_dwordx4 v[140:143], %[pwb], off offset:2096\n"
            "global_load_dwordx4 v[144:147], %[pwc], off\n"
            "global_load_dwordx4 v[148:151], %[pwc], off offset:16\n"
            "global_load_dwordx4 v[152:155], %[pwc], off offset:32\n"
            "global_load_dwordx4 v[156:159], %[pwc], off offset:48\n"
            "global_load_dwordx4 v[160:163], %[pwc], off offset:2048\n"
            "global_load_dwordx4 v[164:167], %[pwc], off offset:2064\n"
            "global_load_dwordx4 v[168:171], %[pwc], off offset:2080\n"
            "global_load_dwordx4 v[172:175], %[pwc], off offset:2096\n"
            "v_mov_b32 v24, %[wb]\n"
            "v_mov_b32 v25, %[hb]\n"
            "v_mov_b32 v26, %[xa]\n"
            "v_mov_b32 v176, %[c0i]\n"
            "v_mov_b32 v177, %[c1]\n"
            "v_mov_b32 v178, %[bb0a]\n"
            "v_mov_b32 v179, 0\n"
            "v_mov_b32 v180, %[bb0b]\n"
            "v_mov_b32 v181, 0\n"
            "v_mov_b32 v182, %[bb1a]\n"
            "v_mov_b32 v183, 0\n"
            "v_mov_b32 v184, %[bb1b]\n"
            "v_mov_b32 v185, 0\n"
            "s_movk_i32 s22, 511\n"
            "s_mov_b32 s20, 0x7fffffff\n"
            "s_mov_b32 s21, 0x4038aa3b\n"       // 2*log2(e)
            "s_waitcnt vmcnt(0)\n"
            "Llstm_%=:\n"
            // ---------- loads (x first for progressive waits) ----------
            "ds_read_b32  v27, v26\n"                  // x[t]
            "ds_read_b128 v[32:35], v25\n"             // h0[0:4)
            "ds_read_b128 v[36:39], v25 offset:16\n"
            "ds_read_b128 v[40:43], v25 offset:32\n"
            "ds_read_b128 v[44:47], v25 offset:48\n"
            "ds_read_b128 v[48:51], v25 offset:64\n"   // h1[0:4)
            "ds_read_b128 v[52:55], v25 offset:80\n"
            "ds_read_b128 v[56:59], v25 offset:96\n"
            "ds_read_b128 v[60:63], v25 offset:112\n"
            "v_add_u32 v26, 4, v26\n"
            // ---------- L0 dots (bias pre-folded in C), progressive waits ----------
            "s_waitcnt lgkmcnt(7)\n"
            "v_pk_fma_f32 v[64:65], v[80:81],  v[32:33], v[178:179]\n"
            "v_pk_fma_f32 v[66:67], v[96:97],  v[32:33], v[180:181]\n"
            "v_pk_fma_f32 v[64:65], v[82:83],  v[34:35], v[64:65]\n"
            "v_pk_fma_f32 v[66:67], v[98:99],  v[34:35], v[66:67]\n"
            "s_waitcnt lgkmcnt(6)\n"
            "v_pk_fma_f32 v[64:65], v[84:85],  v[36:37], v[64:65]\n"
            "v_pk_fma_f32 v[66:67], v[100:101], v[36:37], v[66:67]\n"
            "v_pk_fma_f32 v[64:65], v[86:87],  v[38:39], v[64:65]\n"
            "v_pk_fma_f32 v[66:67], v[102:103], v[38:39], v[66:67]\n"
            "s_waitcnt lgkmcnt(5)\n"
            "v_pk_fma_f32 v[64:65], v[88:89],  v[40:41], v[64:65]\n"
            "v_pk_fma_f32 v[66:67], v[104:105], v[40:41], v[66:67]\n"
            "v_pk_fma_f32 v[64:65], v[90:91],  v[42:43], v[64:65]\n"
            "v_pk_fma_f32 v[66:67], v[106:107], v[42:43], v[66:67]\n"
            "s_waitcnt lgkmcnt(4)\n"
            "v_pk_fma_f32 v[64:65], v[92:93],  v[44:45], v[64:65]\n"
            "v_pk_fma_f32 v[66:67], v[108:109], v[44:45], v[66:67]\n"
            "v_pk_fma_f32 v[64:65], v[94:95],  v[46:47], v[64:65]\n"
            "v_pk_fma_f32 v[66:67], v[110:111], v[46:47], v[66:67]\n"
            // ---------- L0 finish + acts ----------
            "v_add_f32 v28, v64, v65\n"
            "v_add_f32 v29, v66, v67\n"
            "v_fmac_f32 v28, v27, %[wxa]\n"
            "v_fmac_f32 v29, v27, %[wxb]\n"
            "v_mul_f32 v72, %[nl2e], v28\n"
            "v_mul_f32 v73, %[Ca1], v29\n"
            "v_exp_f32 v72, v72\n"
            "v_exp_f32 v73, v73\n"
            "v_add_f32 v72, 1.0, v72\n"
            "v_add_f32 v73, 1.0, v73\n"
            "v_rcp_f32 v72, v72\n"
            "v_rcp_f32 v73, v73\n"
            "s_nop 0\n"
            "v_fma_f32 v73, %[Aa1], v73, %[Ba1]\n"
            "v_mul_f32 v28, v72, v73\n"                // p0 = i0*g0 (half0)
            "ds_swizzle_b32 v76, v28 offset:0x401F\n"  // p0 -> half1
            // ---------- L1 dots part A (wb x h0) -- hides swizzle+trans ----------
            "v_pk_fma_f32 v[68:69], v[112:113], v[32:33], v[182:183]\n"
            "v_pk_fma_f32 v[70:71], v[128:129], v[32:33], v[184:185]\n"
            "v_pk_fma_f32 v[68:69], v[114:115], v[34:35], v[68:69]\n"
            "v_pk_fma_f32 v[70:71], v[130:131], v[34:35], v[70:71]\n"
            "v_pk_fma_f32 v[68:69], v[116:117], v[36:37], v[68:69]\n"
            "v_pk_fma_f32 v[70:71], v[132:133], v[36:37], v[70:71]\n"
            "v_pk_fma_f32 v[68:69], v[118:119], v[38:39], v[68:69]\n"
            "v_pk_fma_f32 v[70:71], v[134:135], v[38:39], v[70:71]\n"
            "v_pk_fma_f32 v[68:69], v[120:121], v[40:41], v[68:69]\n"
            "v_pk_fma_f32 v[70:71], v[136:137], v[40:41], v[70:71]\n"
            "v_pk_fma_f32 v[68:69], v[122:123], v[42:43], v[68:69]\n"
            "v_pk_fma_f32 v[70:71], v[138:139], v[42:43], v[70:71]\n"
            "v_pk_fma_f32 v[68:69], v[124:125], v[44:45], v[68:69]\n"
            "v_pk_fma_f32 v[70:71], v[140:141], v[44:45], v[70:71]\n"
            "v_pk_fma_f32 v[68:69], v[126:127], v[46:47], v[68:69]\n"
            "v_pk_fma_f32 v[70:71], v[142:143], v[46:47], v[70:71]\n"
            // ---------- L0 state on half1: c0 = f0*c0 + p0; h0 = o0*tanh(c0) ----------
            "s_waitcnt lgkmcnt(0)\n"                   // swizzle + h1 reads done
            "v_fma_f32 v176, v72, v176, v76\n"
            "v_mul_f32 v29, s21, |v176|\n"
            "v_exp_f32 v29, v29\n"
            "s_nop 0\n"
            "v_add_f32 v29, 1.0, v29\n"
            "v_rcp_f32 v29, v29\n"
            "s_nop 0\n"
            "v_fma_f32 v29, -2.0, v29, 1.0\n"
            "v_bfi_b32 v29, s20, v29, v176\n"
            "v_mul_f32 v28, v73, v29\n"                // h0n (half1: v73 = o0)
            "ds_write_b32 v24, v28\n"
            // ---------- L1 dots part B (wc x h1) ----------
            "v_pk_fma_f32 v[68:69], v[144:145], v[48:49], v[68:69]\n"
            "v_pk_fma_f32 v[70:71], v[160:161], v[48:49], v[70:71]\n"
            "v_pk_fma_f32 v[68:69], v[146:147], v[50:51], v[68:69]\n"
            "v_pk_fma_f32 v[70:71], v[162:163], v[50:51], v[70:71]\n"
            "v_pk_fma_f32 v[68:69], v[148:149], v[52:53], v[68:69]\n"
            "v_pk_fma_f32 v[70:71], v[164:165], v[52:53], v[70:71]\n"
            "v_pk_fma_f32 v[68:69], v[150:151], v[54:55], v[68:69]\n"
            "v_pk_fma_f32 v[70:71], v[166:167], v[54:55], v[70:71]\n"
            "v_pk_fma_f32 v[68:69], v[152:153], v[56:57], v[68:69]\n"
            "v_pk_fma_f32 v[70:71], v[168:169], v[56:57], v[70:71]\n"
            "v_pk_fma_f32 v[68:69], v[154:155], v[58:59], v[68:69]\n"
            "v_pk_fma_f32 v[70:71], v[170:171], v[58:59], v[70:71]\n"
            "v_pk_fma_f32 v[68:69], v[156:157], v[60:61], v[68:69]\n"
            "v_pk_fma_f32 v[70:71], v[172:173], v[60:61], v[70:71]\n"
            "v_pk_fma_f32 v[68:69], v[158:159], v[62:63], v[68:69]\n"
            "v_pk_fma_f32 v[70:71], v[174:175], v[62:63], v[70:71]\n"
            // ---------- L1 finish + acts ----------
            "v_add_f32 v30, v68, v69\n"
            "v_add_f32 v31, v70, v71\n"
            "v_mul_f32 v74, %[nl2e], v30\n"
            "v_mul_f32 v75, %[Ca1], v31\n"
            "v_exp_f32 v74, v74\n"
            "v_exp_f32 v75, v75\n"
            "v_add_f32 v74, 1.0, v74\n"
            "v_add_f32 v75, 1.0, v75\n"
            "v_rcp_f32 v74, v74\n"
            "v_rcp_f32 v75, v75\n"
            "s_nop 0\n"
            "v_fma_f32 v75, %[Aa1], v75, %[Ba1]\n"
            "v_mul_f32 v30, v74, v75\n"                // p1 = i1*g1 (half0)
            "ds_swizzle_b32 v78, v30 offset:0x401F\n"  // p1 -> half1
            // ---------- L1 state on half1 ----------
            "s_waitcnt lgkmcnt(0)\n"
            "v_fma_f32 v177, v74, v177, v78\n"         // c1 = f1*c1 + p1
            "v_mul_f32 v29, s21, |v177|\n"
            "v_exp_f32 v29, v29\n"
            "s_nop 0\n"
            "v_add_f32 v29, 1.0, v29\n"
            "v_rcp_f32 v29, v29\n"
            "s_nop 0\n"
            "v_fma_f32 v29, -2.0, v29, 1.0\n"
            "v_bfi_b32 v29, s20, v29, v177\n"
            "v_mul_f32 v29, v75, v29\n"                // h1n = o1*tanh(c1)
            "ds_write_b32 v24, v29 offset:64\n"
            // ---------- loop ----------
            "s_sub_u32 s22, s22, 1\n"
            "s_cmp_lg_u32 s22, 0\n"
            "s_cbranch_scc1 Llstm_%=\n"
            "v_mov_b32 %[c1], v177\n"
            : [c1]"+v"(cs1)
            : [hb]"v"(hb), [xa]"v"(xa), [wb]"v"(wb_),
              [pwa]"v"(pwa), [pwb]"v"(pwb), [pwc]"v"(pwc),
              [bb0a]"v"(bb0a), [bb0b]"v"(bb0b), [bb1a]"v"(bb1a), [bb1b]"v"(bb1b),
              [wxa]"v"(wxa), [wxb]"v"(wxb), [nl2e]"v"(nl2e),
              [Ca1]"v"(Ca1), [Aa1]"v"(Aa1), [Ba1]"v"(Ba1), [c0i]"v"(cs0)
            : "memory", "scc", "s20", "s21", "s22",
              "v24","v25","v26","v27","v28","v29","v30","v31",
              "v32","v33","v34","v35","v36","v37","v38","v39",
              "v40","v41","v42","v43","v44","v45","v46","v47",
              "v48","v49","v50","v51","v52","v53","v54","v55",
              "v56","v57","v58","v59","v60","v61","v62","v63",
              "v64","v65","v66","v67","v68","v69","v70","v71",
              "v72","v73","v74","v75","v76","v77","v78","v79",
              "v80","v81","v82","v83","v84","v85","v86","v87",
              "v88","v89","v90","v91","v92","v93","v94","v95",
              "v96","v97","v98","v99","v100","v101","v102","v103",
              "v104","v105","v106","v107","v108","v109","v110","v111",
              "v112","v113","v114","v115","v116","v117","v118","v119",
              "v120","v121","v122","v123","v124","v125","v126","v127",
              "v128","v129","v130","v131","v132","v133","v134","v135",
              "v136","v137","v138","v139","v140","v141","v142","v143",
              "v144","v145","v146","v147","v148","v149","v150","v151",
              "v152","v153","v154","v155","v156","v157","v158","v159",
              "v160","v161","v162","v163","v164","v165","v166","v167",
              "v168","v169","v170","v171","v172","v173","v174","v175",
              "v176","v177","v178","v179","v180","v181","v182","v183",
              "v184","v185");
    }

    // ---- final L1 step (t=511): recomputed from laundered lane id ----
    {
        int l2 = __builtin_amdgcn_workitem_id_x();
        asm("" : "+v"(l2));                    // block CSE with pre-asm values
        const int grp2  = l2 >> 5;
        const int half2 = (l2 >> 4) & 1;
        const int j2    = l2 & 15;
        const int rb0 = half2 * 16 + j2;
        const int rb1 = rb0 + 32;
        const float Ca2 = half2 ? (-LOG2E) : (-2.0f * LOG2E);
        const float Aa2 = half2 ? 1.0f : 2.0f;
        const float Ba2 = half2 ? 0.0f : -1.0f;

        float a1a = b_ih1[rb0] + b_hh1[rb0];
        float a1b = b_ih1[rb1] + b_hh1[rb1];
        const float* h0p = &lds[grp2 * 40];
        const float* h1p = h0p + 16;
        #pragma unroll
        for (int k = 0; k < 16; ++k) {
            const float h0k = h0p[k], h1k = h1p[k];
            a1a = fmaf(W_ih1[rb0 * 16 + k], h0k, a1a);
            a1b = fmaf(W_ih1[rb1 * 16 + k], h0k, a1b);
            a1a = fmaf(W_hh1[rb0 * 16 + k], h1k, a1a);
            a1b = fmaf(W_hh1[rb1 * 16 + k], h1k, a1b);
        }
        const float s0 = fast_rcp(1.0f + fast_exp2(a1a * (-LOG2E)));            // i1 / f1
        const float s1 = fmaf(Aa2, fast_rcp(1.0f + fast_exp2(a1b * Ca2)), Ba2);  // g1 / o1
        const float p1  = s0 * s1;                    // half0: i1*g1
        const float psw = __shfl_xor(p1, 16);         // half1 receives i1*g1
        const float c1f = fmaf(s0, cs1, psw);         // half1: f1*c1 + i1*g1
        const float e = fast_exp2(fabsf(c1f) * (2.0f * LOG2E));
        float th = fmaf(-2.0f, fast_rcp(e + 1.0f), 1.0f);
        th = copysignf(th, c1f);
        const float h1fin = s1 * th;                  // half1: o1*tanh(c1)

        // FC: out[2*bid+grp] = sum_j h1_j * W_fc[j] + b_fc (per 32-lane group)
        float p = (half2 == 1) ? h1fin * W_fc[j2] : 0.0f;
        p += __shfl_xor(p, 1);
        p += __shfl_xor(p, 2);
        p += __shfl_xor(p, 4);
        p += __shfl_xor(p, 8);
        p += __shfl_xor(p, 16);
        if ((l2 & 31) == 0) out[2 * bid + grp2] = p + b_fc[0];
    }
}

extern "C" void kernel_launch(void* const* d_in, const int* in_sizes, int n_in,
                              void* d_out, int out_size, void* d_ws, size_t ws_size,
                              hipStream_t stream) {
    const float* x     = (const float*)d_in[0];
    const float* W_ih0 = (const float*)d_in[1];
    const float* W_hh0 = (const float*)d_in[2];
    const float* b_ih0 = (const float*)d_in[3];
    const float* b_hh0 = (const float*)d_in[4];
    const float* W_ih1 = (const float*)d_in[5];
    const float* W_hh1 = (const float*)d_in[6];
    const float* b_ih1 = (const float*)d_in[7];
    const float* b_hh1 = (const float*)d_in[8];
    const float* W_fc  = (const float*)d_in[9];
    const float* b_fc  = (const float*)d_in[10];
    float* out = (float*)d_out;

    dim3 grid(2048), block(64);
    hipLaunchKernelGGL(lstm2_wave, grid, block, 0, stream,
                       x, W_ih0, W_hh0, b_ih0, b_hh0,
                       W_ih1, W_hh1, b_ih1, b_hh1, W_fc, b_fc, out);
}